// Round 4
// baseline (256.968 us; speedup 1.0000x reference)
//
#include <hip/hip_runtime.h>
#include <hip/hip_cooperative_groups.h>

namespace cg = cooperative_groups;

// Shapes (fixed by the problem)
#define B_ 2
#define S_ 2048
#define D_ 1024
#define H_ 16
#define HS_ 64
#define HD_ 1024     // H_*HS_
#define BS_ (B_*S_)  // 4096 flattened rows
#define KS_ 64       // pipelined K-step
#define TP2_ 264     // padded row length (elems) for kv transposed LDS tiles (256+8)

typedef __attribute__((ext_vector_type(8))) short short8_t;   // 8 bf16 (MFMA A/B frag)
typedef __attribute__((ext_vector_type(4))) float float4_t;   // MFMA C/D frag

__device__ inline unsigned short f32_to_bf16(float f) {
  unsigned int u = __float_as_uint(f);
  u += 0x7FFF + ((u >> 16) & 1);   // round-to-nearest-even
  return (unsigned short)(u >> 16);
}

// async global->LDS, 16B per lane. LDS dest is wave-uniform base + lane*16.
__device__ inline void async_copy16(const void* g, void* lds) {
  __builtin_amdgcn_global_load_lds(
      (const __attribute__((address_space(1))) void*)g,
      (__attribute__((address_space(3))) void*)lds, 16, 0, 0);
}

#define WAITV6 asm volatile("s_waitcnt vmcnt(6)" ::: "memory")
#define WAITV4 asm volatile("s_waitcnt vmcnt(4)" ::: "memory")
#define WAITV0 asm volatile("s_waitcnt vmcnt(0)" ::: "memory")
#define WAITL0 asm volatile("s_waitcnt lgkmcnt(0)" ::: "memory")
#define BAR    __builtin_amdgcn_s_barrier()
#define SCHEDB __builtin_amdgcn_sched_barrier(0)
#define PRIO1  __builtin_amdgcn_s_setprio(1)
#define PRIO0  __builtin_amdgcn_s_setprio(0)

// XOR swizzle (8-chunk rows at KS_=64): LDS[row][phys chunk c] holds global
// chunk c ^ (row&7). Frag read of logical chunk q (=ks*4+quad, 0..7) from row
// R is at phys q ^ (R&7). Across a 16-lane group R&7 sweeps 8 values -> 32
// banks covered, 2 lanes/bank = free (m136). Same involution on both sides.

// ---------------------------------------------------------------------------
// FUSED cooperative kernel: 256 blocks x 512 threads (1 block/CU, forced by
// 144 KB LDS). Stages separated by grid.sync() instead of kernel launches:
//   S0 prep      : x fp32->bf16 (8 float4 units/thread) + Wkvt build
//   S1 kv_mfma   : [256 s x 128] = x-tile @ Wkvt_h, deep 3-slot pipeline
//                  (verbatim R9 body), then K^T V -> Mpart, V -> Vb
//   S2 m_reduce  : M[b,h] = 0.125 * sum of 16 stile slots
//   S3 p         : P = M @ Wproj -> Pt transposed bf16 (2 virtual blocks per
//                  real block, one per 256-thread half)
//   S4 out_mfma  : out = Vb @ Pt^T + bias, deep 3-slot pipeline (verbatim R9)
// ---------------------------------------------------------------------------
__global__ __launch_bounds__(512) void fused_kernel(
    const float* __restrict__ x, const float* __restrict__ Wk,
    const float* __restrict__ Wv, const float* __restrict__ Wproj,
    const float* __restrict__ bproj,
    unsigned short* __restrict__ xb,    // [4096][1024] bf16
    unsigned short* __restrict__ Wkvt,  // [16][128][1024] bf16
    unsigned short* __restrict__ Vb,    // [4096][1024] bf16
    float* __restrict__ Mpart,          // [32][16][64][64]
    float* __restrict__ M,              // [2][16][64][64]
    unsigned short* __restrict__ Pt,    // [2][1024][1024] bf16
    float* __restrict__ out) {          // [4096][1024]
  const int blk = blockIdx.x;   // 0..255
  const int tid = threadIdx.x;  // 0..511
  __shared__ __align__(16) unsigned char smem[147456];
  cg::grid_group grid = cg::this_grid();

  // ======================= S0: prep =======================
  {
    // x fp32 -> bf16: 1,048,576 float4 units over 131072 threads.
#pragma unroll
    for (int u = 0; u < 8; ++u) {
      int idx = (blk * 512 + tid) + u * 131072;
      float4 v = ((const float4*)x)[idx];
      ushort4 o;
      o.x = f32_to_bf16(v.x); o.y = f32_to_bf16(v.y);
      o.z = f32_to_bf16(v.z); o.w = f32_to_bf16(v.w);
      ((ushort4*)xb)[idx] = o;
    }
    // Wkvt build: block = (h, d0) exactly as the old 256-block prep tail.
    float (*lds)[65] = (float(*)[65])smem;
    const int h = blk >> 4;
    const int d0 = (blk & 15) * 64;
    // K half
#pragma unroll
    for (int i = 0; i < 8; ++i) {
      int idx = tid + i * 512; int dd = idx >> 6, e = idx & 63;
      lds[e][dd] = Wk[((size_t)h * D_ + d0 + dd) * HS_ + e];
    }
    __syncthreads();
#pragma unroll
    for (int i = 0; i < 8; ++i) {
      int idx = tid + i * 512; int e = idx >> 6, dd = idx & 63;
      Wkvt[((size_t)h * 128 + e) * D_ + d0 + dd] = f32_to_bf16(lds[e][dd]);
    }
    __syncthreads();
    // V half
#pragma unroll
    for (int i = 0; i < 8; ++i) {
      int idx = tid + i * 512; int dd = idx >> 6, e = idx & 63;
      lds[e][dd] = Wv[((size_t)h * D_ + d0 + dd) * HS_ + e];
    }
    __syncthreads();
#pragma unroll
    for (int i = 0; i < 8; ++i) {
      int idx = tid + i * 512; int e = idx >> 6, dd = idx & 63;
      Wkvt[((size_t)h * 128 + 64 + e) * D_ + d0 + dd] = f32_to_bf16(lds[e][dd]);
    }
  }
  grid.sync();

  // ======================= S1: kv_mfma (R9 body) =======================
  {
    const int stile = blk & 15;
    const int h = blk >> 4;
    const int s0 = stile * 256;
    const int lane = tid & 63;
    const int wid = tid >> 6;                  // 0..7
    const int wm = wid >> 1, wn = wid & 1;     // 4(M) x 2(N)
    const int quad = lane >> 4, l16 = lane & 15;
    const int xa = l16 & 7;                    // frag-read swizzle key

    unsigned short* const Ktl = (unsigned short*)smem;
    unsigned short* const Vtl = (unsigned short*)(smem + 64 * TP2_ * 2);

    float4_t acc[4][4];
    const float4_t fz = {0.f, 0.f, 0.f, 0.f};
#pragma unroll
    for (int i = 0; i < 4; ++i)
#pragma unroll
      for (int j = 0; j < 4; ++j) acc[i][j] = fz;

    unsigned short* pc = (unsigned short*)(smem);            // tile kt
    unsigned short* pn = (unsigned short*)(smem + 49152);    // tile kt+1
    unsigned short* ps = (unsigned short*)(smem + 98304);    // tile kt+2

    // One stage unit = 64 rows x 64 k (8 KB) moved by all 512 threads.
    // u<4: A quarters (256 s rows); u>=4: B halves (128 Wkvt rows).
    auto stageu = [&](unsigned short* slot, int kt, int u) {
      const int k0 = kt * KS_;
      if (u < 4) {
        int rb = u * 64 + wid * 8;
        int r = rb + (lane >> 3);
        int ch = ((lane & 7) ^ (r & 7)) * 8;     // pre-swizzled global chunk
        async_copy16(xb + (size_t)(s0 + r) * D_ + k0 + ch, slot + rb * KS_);
      } else {
        int rb = (u - 4) * 64 + wid * 8;
        int r = rb + (lane >> 3);
        int ch = ((lane & 7) ^ (r & 7)) * 8;
        async_copy16(Wkvt + ((size_t)h * 128 + r) * D_ + k0 + ch,
                     slot + 16384 + rb * KS_);
      }
    };
    auto rdA = [&](const unsigned short* P, int mi, int ks) {
      return *(const short8_t*)(P + (wm * 64 + mi * 16 + l16) * KS_ +
                                ((ks * 4 + quad) ^ xa) * 8);
    };
    auto rdB = [&](const unsigned short* P, int ni, int ks) {
      return *(const short8_t*)(P + 16384 + (wn * 64 + ni * 16 + l16) * KS_ +
                                ((ks * 4 + quad) ^ xa) * 8);
    };

    short8_t a0[4], a1[4], b0[4], b1[4];

    // Prologue: tiles 0 and 1 fully staged (12 loads in flight / thread).
#pragma unroll
    for (int u = 0; u < 6; ++u) stageu(pc, 0, u);
#pragma unroll
    for (int u = 0; u < 6; ++u) stageu(pn, 1, u);
    WAITV6;                                 // drain tile 0, keep tile 1 in flight
    BAR;
#pragma unroll
    for (int mi = 0; mi < 4; ++mi) a0[mi] = rdA(pc, mi, 0);
    b0[0] = rdB(pc, 0, 0); b0[1] = rdB(pc, 1, 0);

    for (int kt = 0; kt < 16; ++kt) {
      const bool st = (kt < 14);
      // ---- q0: MFMA (ks0, n-half0); read b(ks0, n-half1) ----
      if (st) { stageu(ps, kt + 2, 0); stageu(ps, kt + 2, 1); }
      BAR; WAITL0; SCHEDB;
      PRIO1;
#pragma unroll
      for (int mi = 0; mi < 4; ++mi) {
        acc[mi][0] = __builtin_amdgcn_mfma_f32_16x16x32_bf16(a0[mi], b0[0], acc[mi][0], 0, 0, 0);
        acc[mi][1] = __builtin_amdgcn_mfma_f32_16x16x32_bf16(a0[mi], b0[1], acc[mi][1], 0, 0, 0);
      }
      PRIO0;
      b0[2] = rdB(pc, 2, 0); b0[3] = rdB(pc, 3, 0);
      // ---- q1: MFMA (ks0, n-half1); read a,b (ks1, n-half0) ----
      if (st) { stageu(ps, kt + 2, 2); stageu(ps, kt + 2, 3); }
      BAR; WAITL0; SCHEDB;
      PRIO1;
#pragma unroll
      for (int mi = 0; mi < 4; ++mi) {
        acc[mi][2] = __builtin_amdgcn_mfma_f32_16x16x32_bf16(a0[mi], b0[2], acc[mi][2], 0, 0, 0);
        acc[mi][3] = __builtin_amdgcn_mfma_f32_16x16x32_bf16(a0[mi], b0[3], acc[mi][3], 0, 0, 0);
      }
      PRIO0;
#pragma unroll
      for (int mi = 0; mi < 4; ++mi) a1[mi] = rdA(pc, mi, 1);
      b1[0] = rdB(pc, 0, 1); b1[1] = rdB(pc, 1, 1);
      // ---- q2: MFMA (ks1, n-half0); read b(ks1, n-half1) ----
      if (st) stageu(ps, kt + 2, 4);
      BAR; WAITL0; SCHEDB;
      PRIO1;
#pragma unroll
      for (int mi = 0; mi < 4; ++mi) {
        acc[mi][0] = __builtin_amdgcn_mfma_f32_16x16x32_bf16(a1[mi], b1[0], acc[mi][0], 0, 0, 0);
        acc[mi][1] = __builtin_amdgcn_mfma_f32_16x16x32_bf16(a1[mi], b1[1], acc[mi][1], 0, 0, 0);
      }
      PRIO0;
      b1[2] = rdB(pc, 2, 1); b1[3] = rdB(pc, 3, 1);
      // ---- q3: drain tile kt+1; MFMA (ks1, n-half1); boundary read kt+1 ----
      if (st) stageu(ps, kt + 2, 5);
      if (kt < 14) { WAITV6; } else if (kt == 14) { WAITV0; }
      BAR; WAITL0; SCHEDB;
      PRIO1;
#pragma unroll
      for (int mi = 0; mi < 4; ++mi) {
        acc[mi][2] = __builtin_amdgcn_mfma_f32_16x16x32_bf16(a1[mi], b1[2], acc[mi][2], 0, 0, 0);
        acc[mi][3] = __builtin_amdgcn_mfma_f32_16x16x32_bf16(a1[mi], b1[3], acc[mi][3], 0, 0, 0);
      }
      PRIO0;
      if (kt < 15) {
#pragma unroll
        for (int mi = 0; mi < 4; ++mi) a0[mi] = rdA(pn, mi, 0);
        b0[0] = rdB(pn, 0, 0); b0[1] = rdB(pn, 1, 0);
      }
      unsigned short* t = pc; pc = pn; pn = ps; ps = t;
    }
    __syncthreads();   // all waves' last frag reads done before LDS reuse

    // ---- phase 2a: dump quadrants transposed into LDS (bf16) ----
    {
      unsigned short* dstT = (wn == 0) ? Ktl : Vtl;
#pragma unroll
      for (int mi = 0; mi < 4; ++mi)
#pragma unroll
        for (int ni = 0; ni < 4; ++ni) {
          int f = ni * 16 + l16;
          int sm = wm * 64 + mi * 16 + quad * 4;   // 0..255
          ushort4 o;
          o.x = f32_to_bf16(acc[mi][ni][0]);
          o.y = f32_to_bf16(acc[mi][ni][1]);
          o.z = f32_to_bf16(acc[mi][ni][2]);
          o.w = f32_to_bf16(acc[mi][ni][3]);
          *(ushort4*)&dstT[f * TP2_ + sm] = o;
        }
    }
    __syncthreads();

    // ---- phase 2b: Vb[s0+s][h*64+e] from Vtl (16B stores) ----
#pragma unroll
    for (int u = 0; u < 4; ++u) {
      int unit = tid + u * 512;            // 0..2047 = 256 s x 8 e-chunks
      int s = unit & 255;
      int ec = (unit >> 8) * 8;
      union { unsigned short u16[8]; uint4 v; } tv;
#pragma unroll
      for (int e = 0; e < 8; ++e) tv.u16[e] = Vtl[(ec + e) * TP2_ + s];
      *(uint4*)&Vb[(size_t)(s0 + s) * HD_ + h * 64 + ec] = tv.v;
    }

    // ---- phase 2c: Mpart[slot][f][e], slot = stile*2 + half ----
    {
      const int half = wid >> 2, fq = wid & 3;
      float4_t macc[4];
#pragma unroll
      for (int ni = 0; ni < 4; ++ni) macc[ni] = fz;
#pragma unroll
      for (int ss = 0; ss < 4; ++ss) {     // 4 k-steps of 32 s
        short8_t ka = *(const short8_t*)&Ktl[(fq * 16 + l16) * TP2_ +
                                             half * 128 + ss * 32 + quad * 8];
#pragma unroll
        for (int ni = 0; ni < 4; ++ni) {
          short8_t vv = *(const short8_t*)&Vtl[(ni * 16 + l16) * TP2_ +
                                               half * 128 + ss * 32 + quad * 8];
          macc[ni] = __builtin_amdgcn_mfma_f32_16x16x32_bf16(ka, vv, macc[ni], 0, 0, 0);
        }
      }
      float* mdst = Mpart + (((size_t)(stile * 2 + half)) * H_ + h) * 4096;
#pragma unroll
      for (int ni = 0; ni < 4; ++ni) {
        int e = ni * 16 + l16;
#pragma unroll
        for (int r = 0; r < 4; ++r) {
          int f = fq * 16 + quad * 4 + r;
          mdst[f * 64 + e] = macc[ni][r];
        }
      }
    }
  }
  grid.sync();

  // ======================= S2: m_reduce =======================
  {
    int gid = blk * 512 + tid;
    if (gid < 32768) {
      const int e0 = gid * 4;               // [0, 131072)
      const int bh = e0 >> 12;              // b*16+h
      const int idx = e0 & 4095;
      const int b = bh >> 4, h = bh & 15;
      float4 s = {0.f, 0.f, 0.f, 0.f};
#pragma unroll
      for (int p = 0; p < 16; ++p) {
        const float4 v =
            *(const float4*)&Mpart[(((size_t)(b * 16 + p)) * H_ + h) * 4096 + idx];
        s.x += v.x; s.y += v.y; s.z += v.z; s.w += v.w;
      }
      s.x *= 0.125f; s.y *= 0.125f; s.z *= 0.125f; s.w *= 0.125f;
      *(float4*)&M[(size_t)bh * 4096 + idx] = s;
    }
  }
  grid.sync();

  // ======================= S3: p (2 virtual blocks / block) =======================
  {
    const int sel = tid >> 8;            // 0 or 1: which virtual block
    const int tid2 = tid & 255;
    const int vb = blk * 2 + sel;        // 0..511
    const int dtile = vb & 15;
    const int h = (vb >> 4) & 15;
    const int b = vb >> 8;
    const int d0 = dtile * 64;
    const int tx = tid2 & 15, ty = tid2 >> 4;
    float (*Ms)[68] = (float(*)[68])(smem + (size_t)sel * 34816);            // [64][68]
    float (*Ws)[68] = (float(*)[68])(smem + (size_t)sel * 34816 + 17408);    // [64][68]
    const size_t mbase = ((size_t)(b * H_ + h)) * HS_ * HS_;
#pragma unroll
    for (int i = 0; i < 16; ++i) {
      int idx = tid2 + i * 256;
      int f = idx >> 6, e = idx & 63;
      Ms[e][f] = M[mbase + idx];
      Ws[f][e] = Wproj[(size_t)(h * HS_ + f) * D_ + d0 + e];
    }
    __syncthreads();
    float acc[4][4] = {};
#pragma unroll
    for (int kk = 0; kk < 64; ++kk) {
      const float4 a4 = *(const float4*)&Ms[kk][ty * 4];
      const float4 b4 = *(const float4*)&Ws[kk][tx * 4];
      const float a[4] = {a4.x, a4.y, a4.z, a4.w};
      const float bb[4] = {b4.x, b4.y, b4.z, b4.w};
#pragma unroll
      for (int i = 0; i < 4; ++i)
#pragma unroll
        for (int j = 0; j < 4; ++j) acc[i][j] += a[i] * bb[j];
    }
    // transpose through LDS: trans[d][f] then linear bf16 rows
    __syncthreads();
#pragma unroll
    for (int i = 0; i < 4; ++i)
#pragma unroll
      for (int j = 0; j < 4; ++j)
        Ms[tx * 4 + j][ty * 4 + i] = acc[i][j];
    __syncthreads();
    {
      int c = tid2 >> 2, ch = tid2 & 3;  // row c (d-dim), 16-elem chunk of f
      unsigned short* dst = Pt + ((size_t)(b * D_ + d0 + c)) * HD_ + h * 64 + ch * 16;
#pragma unroll
      for (int e = 0; e < 16; ++e) dst[e] = f32_to_bf16(Ms[c][ch * 16 + e]);
    }
  }
  grid.sync();

  // ======================= S4: out_mfma (R9 body) =======================
  {
    const int ntile = blk & 7;               // 1024/128 = 8
    const int stile = blk >> 3;              // 4096/128 = 32
    const int s0 = stile * 128;
    const int n0 = ntile * 128;
    const int b = s0 >> 11;
    const int lane = tid & 63;
    const int wid = tid >> 6;                // 0..7
    const int wm = wid & 1, wn = wid >> 1;   // 2(M) x 4(N)
    const int quad = lane >> 4, l16 = lane & 15;
    const int xa = l16 & 7;

    float4_t acc[4][2];
    const float4_t fz = {0.f, 0.f, 0.f, 0.f};
#pragma unroll
    for (int i = 0; i < 4; ++i)
#pragma unroll
      for (int j = 0; j < 2; ++j) acc[i][j] = fz;

    const unsigned short* Bpanel = Pt + (size_t)b * D_ * HD_;

    unsigned short* pc = (unsigned short*)(smem);
    unsigned short* pn = (unsigned short*)(smem + 32768);
    unsigned short* ps = (unsigned short*)(smem + 65536);

    // One stage unit = 64 rows x 64 k (8 KB). u<2: A (Vb); u>=2: B (Pt).
    auto stageu = [&](unsigned short* slot, int kt, int u) {
      const int k0 = kt * KS_;
      if (u < 2) {
        int rb = u * 64 + wid * 8;
        int r = rb + (lane >> 3);
        int ch = ((lane & 7) ^ (r & 7)) * 8;
        async_copy16(Vb + (size_t)(s0 + r) * HD_ + k0 + ch, slot + rb * KS_);
      } else {
        int rb = (u - 2) * 64 + wid * 8;
        int r = rb + (lane >> 3);
        int ch = ((lane & 7) ^ (r & 7)) * 8;
        async_copy16(Bpanel + (size_t)(n0 + r) * HD_ + k0 + ch,
                     slot + 8192 + rb * KS_);
      }
    };
    auto rdA = [&](const unsigned short* P, int mi, int ks) {
      return *(const short8_t*)(P + (wm * 64 + mi * 16 + l16) * KS_ +
                                ((ks * 4 + quad) ^ xa) * 8);
    };
    auto rdB = [&](const unsigned short* P, int ni, int ks) {
      return *(const short8_t*)(P + 8192 + (wn * 32 + ni * 16 + l16) * KS_ +
                                ((ks * 4 + quad) ^ xa) * 8);
    };

    short8_t a0[4], a1[4], b0[2], b1[2];

#pragma unroll
    for (int u = 0; u < 4; ++u) stageu(pc, 0, u);
#pragma unroll
    for (int u = 0; u < 4; ++u) stageu(pn, 1, u);
    WAITV4;
    BAR;
#pragma unroll
    for (int mi = 0; mi < 4; ++mi) a0[mi] = rdA(pc, mi, 0);
    b0[0] = rdB(pc, 0, 0); b0[1] = rdB(pc, 1, 0);

    for (int kt = 0; kt < 16; ++kt) {
      const bool st = (kt < 14);
      // ---- q0: MFMA ks0; read ks1 frags ----
      if (st) { stageu(ps, kt + 2, 0); stageu(ps, kt + 2, 1); }
      BAR; WAITL0; SCHEDB;
      PRIO1;
#pragma unroll
      for (int mi = 0; mi < 4; ++mi) {
        acc[mi][0] = __builtin_amdgcn_mfma_f32_16x16x32_bf16(a0[mi], b0[0], acc[mi][0], 0, 0, 0);
        acc[mi][1] = __builtin_amdgcn_mfma_f32_16x16x32_bf16(a0[mi], b0[1], acc[mi][1], 0, 0, 0);
      }
      PRIO0;
#pragma unroll
      for (int mi = 0; mi < 4; ++mi) a1[mi] = rdA(pc, mi, 1);
      b1[0] = rdB(pc, 0, 1); b1[1] = rdB(pc, 1, 1);
      // ---- q1: drain kt+1; MFMA ks1; boundary read (kt+1, ks0) ----
      if (st) { stageu(ps, kt + 2, 2); stageu(ps, kt + 2, 3); }
      if (kt < 14) { WAITV4; } else if (kt == 14) { WAITV0; }
      BAR; WAITL0; SCHEDB;
      PRIO1;
#pragma unroll
      for (int mi = 0; mi < 4; ++mi) {
        acc[mi][0] = __builtin_amdgcn_mfma_f32_16x16x32_bf16(a1[mi], b1[0], acc[mi][0], 0, 0, 0);
        acc[mi][1] = __builtin_amdgcn_mfma_f32_16x16x32_bf16(a1[mi], b1[1], acc[mi][1], 0, 0, 0);
      }
      PRIO0;
      if (kt < 15) {
#pragma unroll
        for (int mi = 0; mi < 4; ++mi) a0[mi] = rdA(pn, mi, 0);
        b0[0] = rdB(pn, 0, 0); b0[1] = rdB(pn, 1, 0);
      }
      unsigned short* t = pc; pc = pn; pn = ps; ps = t;
    }

#pragma unroll
    for (int ni = 0; ni < 2; ++ni) {
      int col = n0 + wn * 32 + ni * 16 + l16;
      float bias = bproj[col];
#pragma unroll
      for (int mi = 0; mi < 4; ++mi) {
        int rowb = s0 + wm * 64 + mi * 16 + quad * 4;
#pragma unroll
        for (int r = 0; r < 4; ++r)
          out[(size_t)(rowb + r) * D_ + col] = acc[mi][ni][r] + bias;
      }
    }
  }
}

extern "C" void kernel_launch(void* const* d_in, const int* in_sizes, int n_in,
                              void* d_out, int out_size, void* d_ws, size_t ws_size,
                              hipStream_t stream) {
  const float* x = (const float*)d_in[0];
  const float* Wk = (const float*)d_in[1];
  const float* Wv = (const float*)d_in[2];
  const float* Wproj = (const float*)d_in[3];
  const float* bproj = (const float*)d_in[4];
  float* out = (float*)d_out;

  // Workspace layout (~32.5 MB total); every element written before read.
  char* ws = (char*)d_ws;
  unsigned short* xb = (unsigned short*)ws;                  // 4M bf16 = 8 MB
  unsigned short* Wkvt = xb + (size_t)BS_ * D_;              // 2M bf16 = 4 MB
  unsigned short* Vb = Wkvt + (size_t)H_ * 128 * D_;         // 4M bf16 = 8 MB
  float* Mpart = (float*)(Vb + (size_t)BS_ * HD_);           // 2M f32 = 8 MB  [32][16][4096]
  float* M = Mpart + (size_t)32 * H_ * 4096;                 // 128K f32 = 0.5 MB
  unsigned short* Pt = (unsigned short*)(M + (size_t)B_ * H_ * 4096);  // 2M bf16 = 4 MB

  void* args[] = {(void*)&x,    (void*)&Wk, (void*)&Wv, (void*)&Wproj,
                  (void*)&bproj, (void*)&xb, (void*)&Wkvt, (void*)&Vb,
                  (void*)&Mpart, (void*)&M,  (void*)&Pt,   (void*)&out};
  hipLaunchCooperativeKernel((const void*)fused_kernel, dim3(256), dim3(512),
                             args, 0, stream);
}

// Round 5
// 128.006 us; speedup vs baseline: 2.0075x; 2.0075x over previous
//
#include <hip/hip_runtime.h>

// Shapes (fixed by the problem)
#define B_ 2
#define S_ 2048
#define D_ 1024
#define H_ 16
#define HS_ 64
#define HD_ 1024     // H_*HS_
#define BS_ (B_*S_)  // 4096 flattened rows
#define KS_ 64       // pipelined K-step
#define TP2_ 264     // padded row length (elems) for kv transposed LDS tiles (256+8)

// NOTE (R10 accounting): the timed window contains ~88 us of harness
// workspace-poison fills (2 x 256 MiB @ ~6 TB/s) that we cannot affect.
// Our five kernels were ~41 us of the 129 us baseline. This round: drop
// m_reduce (atomic-accumulate M in kv), XCD-cluster block mapping for L2
// reuse in kv/out. Everything else is the harness-verified R9 structure.

typedef __attribute__((ext_vector_type(8))) short short8_t;   // 8 bf16 (MFMA A/B frag)
typedef __attribute__((ext_vector_type(4))) float float4_t;   // MFMA C/D frag

__device__ inline unsigned short f32_to_bf16(float f) {
  unsigned int u = __float_as_uint(f);
  u += 0x7FFF + ((u >> 16) & 1);   // round-to-nearest-even
  return (unsigned short)(u >> 16);
}

// async global->LDS, 16B per lane. LDS dest is wave-uniform base + lane*16.
__device__ inline void async_copy16(const void* g, void* lds) {
  __builtin_amdgcn_global_load_lds(
      (const __attribute__((address_space(1))) void*)g,
      (__attribute__((address_space(3))) void*)lds, 16, 0, 0);
}

#define WAITV6 asm volatile("s_waitcnt vmcnt(6)" ::: "memory")
#define WAITV4 asm volatile("s_waitcnt vmcnt(4)" ::: "memory")
#define WAITV0 asm volatile("s_waitcnt vmcnt(0)" ::: "memory")
#define WAITL0 asm volatile("s_waitcnt lgkmcnt(0)" ::: "memory")
#define BAR    __builtin_amdgcn_s_barrier()
#define SCHEDB __builtin_amdgcn_sched_barrier(0)
#define PRIO1  __builtin_amdgcn_s_setprio(1)
#define PRIO0  __builtin_amdgcn_s_setprio(0)

// XOR swizzle (8-chunk rows at KS_=64): LDS[row][phys chunk c] holds global
// chunk c ^ (row&7). Frag read of logical chunk q (=ks*4+quad, 0..7) from row
// R is at phys q ^ (R&7). Across a 16-lane group R&7 sweeps 8 values -> 32
// banks covered, 2 lanes/bank = free (m136). Same involution on both sides.

// ---------------------------------------------------------------------------
// prep: blocks [0,4096) convert x fp32->bf16 (4 elems/thread);
// blocks [4096,4352) build Wkvt[h][128][d] bf16 (rows 0-63 = Wk cols,
// rows 64-127 = Wv cols), k(d)-contiguous for kv_mfma B staging;
// blocks [4352,4480) zero M (kv atomic-accumulates into it).
// ---------------------------------------------------------------------------
__global__ __launch_bounds__(256) void prep_kernel(
    const float* __restrict__ x, const float* __restrict__ Wk,
    const float* __restrict__ Wv, unsigned short* __restrict__ xb,
    unsigned short* __restrict__ Wkvt, float* __restrict__ M) {
  const int blk = blockIdx.x;
  const int tid = threadIdx.x;
  __shared__ float lds[64][65];
  if (blk < 4096) {
    int idx = blk * 256 + tid;
    float4 v = ((const float4*)x)[idx];
    ushort4 o;
    o.x = f32_to_bf16(v.x); o.y = f32_to_bf16(v.y);
    o.z = f32_to_bf16(v.z); o.w = f32_to_bf16(v.w);
    ((ushort4*)xb)[idx] = o;
    return;
  }
  if (blk >= 4352) {                       // zero M: 128 blocks x 256 x float4
    int idx = (blk - 4352) * 256 + tid;    // 32768 float4 = 131072 floats
    float4 z = {0.f, 0.f, 0.f, 0.f};
    ((float4*)M)[idx] = z;
    return;
  }
  const int wblk = blk - 4096;
  const int h = wblk >> 4;
  const int d0 = (wblk & 15) * 64;
  // K half
#pragma unroll
  for (int i = 0; i < 16; ++i) {
    int idx = tid + i * 256; int dd = idx >> 6, e = idx & 63;
    lds[e][dd] = Wk[((size_t)h * D_ + d0 + dd) * HS_ + e];
  }
  __syncthreads();
#pragma unroll
  for (int i = 0; i < 16; ++i) {
    int idx = tid + i * 256; int e = idx >> 6, dd = idx & 63;
    Wkvt[((size_t)h * 128 + e) * D_ + d0 + dd] = f32_to_bf16(lds[e][dd]);
  }
  __syncthreads();
  // V half
#pragma unroll
  for (int i = 0; i < 16; ++i) {
    int idx = tid + i * 256; int dd = idx >> 6, e = idx & 63;
    lds[e][dd] = Wv[((size_t)h * D_ + d0 + dd) * HS_ + e];
  }
  __syncthreads();
#pragma unroll
  for (int i = 0; i < 16; ++i) {
    int idx = tid + i * 256; int e = idx >> 6, dd = idx & 63;
    Wkvt[((size_t)h * 128 + 64 + e) * D_ + d0 + dd] = f32_to_bf16(lds[e][dd]);
  }
}

// ---------------------------------------------------------------------------
// kv_mfma (R10 = R9 deep 3-slot pipeline + XCD clustering + atomic M):
//   phase 1: [256 s x 128 (64 K | 64 V)] = x-tile @ Wkvt_h.
//     512 threads, 8 waves as 4(M)x2(N), wave tile 64x64, acc[4][4].
//     3 LDS slots (144 KB), vmcnt(6) once per K-tile, read-ahead frags.
//   phase 2: LDS-transpose K,V; V -> Vb; 0.125*K^T V atomically added to
//     M[b,h] (replaces Mpart + m_reduce).
// grid = 256 blocks (1/CU). Block mapping clusters the 16 h-blocks of each
// stile pair on one XCD (xcd = blk&7 heuristic) so the 512 KB xb strip is
// L2-resident and reused 16x instead of 16 L3 round-trips.
// ---------------------------------------------------------------------------
__global__ __launch_bounds__(512) void kv_mfma_kernel(
    const unsigned short* __restrict__ xb,    // [4096][1024]
    const unsigned short* __restrict__ Wkvt,  // [16][128][1024]
    unsigned short* __restrict__ Vb,          // [4096][1024]
    float* __restrict__ M) {                  // [2][16][64][64]
  const int blk = blockIdx.x;
  const int xcd = blk & 7, o = blk >> 3;     // XCD-cluster remap (bijective)
  const int stile = xcd * 2 + (o & 1);       // 0..15
  const int h = o >> 1;                      // 0..15
  const int s0 = stile * 256;
  const int tid = threadIdx.x;
  const int lane = tid & 63;
  const int wid = tid >> 6;                  // 0..7
  const int wm = wid >> 1, wn = wid & 1;     // 4(M) x 2(N)
  const int quad = lane >> 4, l16 = lane & 15;
  const int xa = l16 & 7;                    // frag-read swizzle key

  // 3 slots x (A 32 KB + B 16 KB) = 144 KB; phase 2 aliases the front as
  // Ktl/Vtl transposed tiles [64][TP2_] (66 KB).
  __shared__ __align__(16) unsigned char smem[147456];
  unsigned short* const Ktl = (unsigned short*)smem;
  unsigned short* const Vtl = (unsigned short*)(smem + 64 * TP2_ * 2);

  float4_t acc[4][4];
  const float4_t fz = {0.f, 0.f, 0.f, 0.f};
#pragma unroll
  for (int i = 0; i < 4; ++i)
#pragma unroll
    for (int j = 0; j < 4; ++j) acc[i][j] = fz;

  unsigned short* pc = (unsigned short*)(smem);            // slot for tile kt
  unsigned short* pn = (unsigned short*)(smem + 49152);    // tile kt+1
  unsigned short* ps = (unsigned short*)(smem + 98304);    // tile kt+2

  // One stage unit = 64 rows x 64 k (8 KB) moved by all 512 threads.
  // u<4: A quarters (256 s rows); u>=4: B halves (128 Wkvt rows).
  auto stageu = [&](unsigned short* slot, int kt, int u) {
    const int k0 = kt * KS_;
    if (u < 4) {
      int rb = u * 64 + wid * 8;
      int r = rb + (lane >> 3);
      int ch = ((lane & 7) ^ (r & 7)) * 8;     // pre-swizzled global chunk
      async_copy16(xb + (size_t)(s0 + r) * D_ + k0 + ch, slot + rb * KS_);
    } else {
      int rb = (u - 4) * 64 + wid * 8;
      int r = rb + (lane >> 3);
      int ch = ((lane & 7) ^ (r & 7)) * 8;
      async_copy16(Wkvt + ((size_t)h * 128 + r) * D_ + k0 + ch,
                   slot + 16384 + rb * KS_);
    }
  };
  auto rdA = [&](const unsigned short* P, int mi, int ks) {
    return *(const short8_t*)(P + (wm * 64 + mi * 16 + l16) * KS_ +
                              ((ks * 4 + quad) ^ xa) * 8);
  };
  auto rdB = [&](const unsigned short* P, int ni, int ks) {
    return *(const short8_t*)(P + 16384 + (wn * 64 + ni * 16 + l16) * KS_ +
                              ((ks * 4 + quad) ^ xa) * 8);
  };

  short8_t a0[4], a1[4], b0[4], b1[4];

  // Prologue: tiles 0 and 1 fully staged (12 loads in flight / thread).
#pragma unroll
  for (int u = 0; u < 6; ++u) stageu(pc, 0, u);
#pragma unroll
  for (int u = 0; u < 6; ++u) stageu(pn, 1, u);
  WAITV6;                                   // drain tile 0, keep tile 1 in flight
  BAR;
#pragma unroll
  for (int mi = 0; mi < 4; ++mi) a0[mi] = rdA(pc, mi, 0);
  b0[0] = rdB(pc, 0, 0); b0[1] = rdB(pc, 1, 0);

  for (int kt = 0; kt < 16; ++kt) {
    const bool st = (kt < 14);
    // ---- q0: MFMA (ks0, n-half0); read b(ks0, n-half1) ----
    if (st) { stageu(ps, kt + 2, 0); stageu(ps, kt + 2, 1); }
    BAR; WAITL0; SCHEDB;
    PRIO1;
#pragma unroll
    for (int mi = 0; mi < 4; ++mi) {
      acc[mi][0] = __builtin_amdgcn_mfma_f32_16x16x32_bf16(a0[mi], b0[0], acc[mi][0], 0, 0, 0);
      acc[mi][1] = __builtin_amdgcn_mfma_f32_16x16x32_bf16(a0[mi], b0[1], acc[mi][1], 0, 0, 0);
    }
    PRIO0;
    b0[2] = rdB(pc, 2, 0); b0[3] = rdB(pc, 3, 0);
    // ---- q1: MFMA (ks0, n-half1); read a,b (ks1, n-half0) ----
    if (st) { stageu(ps, kt + 2, 2); stageu(ps, kt + 2, 3); }
    BAR; WAITL0; SCHEDB;
    PRIO1;
#pragma unroll
    for (int mi = 0; mi < 4; ++mi) {
      acc[mi][2] = __builtin_amdgcn_mfma_f32_16x16x32_bf16(a0[mi], b0[2], acc[mi][2], 0, 0, 0);
      acc[mi][3] = __builtin_amdgcn_mfma_f32_16x16x32_bf16(a0[mi], b0[3], acc[mi][3], 0, 0, 0);
    }
    PRIO0;
#pragma unroll
    for (int mi = 0; mi < 4; ++mi) a1[mi] = rdA(pc, mi, 1);
    b1[0] = rdB(pc, 0, 1); b1[1] = rdB(pc, 1, 1);
    // ---- q2: MFMA (ks1, n-half0); read b(ks1, n-half1) ----
    if (st) stageu(ps, kt + 2, 4);
    BAR; WAITL0; SCHEDB;
    PRIO1;
#pragma unroll
    for (int mi = 0; mi < 4; ++mi) {
      acc[mi][0] = __builtin_amdgcn_mfma_f32_16x16x32_bf16(a1[mi], b1[0], acc[mi][0], 0, 0, 0);
      acc[mi][1] = __builtin_amdgcn_mfma_f32_16x16x32_bf16(a1[mi], b1[1], acc[mi][1], 0, 0, 0);
    }
    PRIO0;
    b1[2] = rdB(pc, 2, 1); b1[3] = rdB(pc, 3, 1);
    // ---- q3: drain tile kt+1; MFMA (ks1, n-half1); boundary read kt+1 ----
    if (st) stageu(ps, kt + 2, 5);
    if (kt < 14) { WAITV6; } else if (kt == 14) { WAITV0; }
    BAR; WAITL0; SCHEDB;
    PRIO1;
#pragma unroll
    for (int mi = 0; mi < 4; ++mi) {
      acc[mi][2] = __builtin_amdgcn_mfma_f32_16x16x32_bf16(a1[mi], b1[2], acc[mi][2], 0, 0, 0);
      acc[mi][3] = __builtin_amdgcn_mfma_f32_16x16x32_bf16(a1[mi], b1[3], acc[mi][3], 0, 0, 0);
    }
    PRIO0;
    if (kt < 15) {
#pragma unroll
      for (int mi = 0; mi < 4; ++mi) a0[mi] = rdA(pn, mi, 0);
      b0[0] = rdB(pn, 0, 0); b0[1] = rdB(pn, 1, 0);
    }
    unsigned short* t = pc; pc = pn; pn = ps; ps = t;
  }
  __syncthreads();   // all waves' last frag reads done before LDS reuse

  // ---- phase 2a: dump quadrants transposed into LDS (bf16) ----
  // C cols: wn==0 -> K features, wn==1 -> V features.
  {
    unsigned short* dstT = (wn == 0) ? Ktl : Vtl;
#pragma unroll
    for (int mi = 0; mi < 4; ++mi)
#pragma unroll
      for (int ni = 0; ni < 4; ++ni) {
        int f = ni * 16 + l16;
        int sm = wm * 64 + mi * 16 + quad * 4;   // 0..255
        ushort4 o4;
        o4.x = f32_to_bf16(acc[mi][ni][0]);
        o4.y = f32_to_bf16(acc[mi][ni][1]);
        o4.z = f32_to_bf16(acc[mi][ni][2]);
        o4.w = f32_to_bf16(acc[mi][ni][3]);
        *(ushort4*)&dstT[f * TP2_ + sm] = o4;
      }
  }
  __syncthreads();

  // ---- phase 2b: Vb[s0+s][h*64+e] from Vtl (16B stores) ----
#pragma unroll
  for (int u = 0; u < 4; ++u) {
    int unit = tid + u * 512;            // 0..2047 = 256 s x 8 e-chunks
    int s = unit & 255;
    int ec = (unit >> 8) * 8;
    union { unsigned short u16[8]; uint4 v; } tv;
#pragma unroll
    for (int e = 0; e < 8; ++e) tv.u16[e] = Vtl[(ec + e) * TP2_ + s];
    *(uint4*)&Vb[(size_t)(s0 + s) * HD_ + h * 64 + ec] = tv.v;
  }

  // ---- phase 2c: M[b,h] += 0.125 * K^T V over this block's two 128-row
  // halves (slot = stile*2+half; b = slot>>4). HW f32 atomics; ~8 blocks
  // contend per (b,h) plane. Replaces Mpart + m_reduce. ----
  {
    const int half = wid >> 2, fq = wid & 3;
    float4_t macc[4];
#pragma unroll
    for (int ni = 0; ni < 4; ++ni) macc[ni] = fz;
#pragma unroll
    for (int ss = 0; ss < 4; ++ss) {     // 4 k-steps of 32 s
      short8_t ka = *(const short8_t*)&Ktl[(fq * 16 + l16) * TP2_ +
                                           half * 128 + ss * 32 + quad * 8];
#pragma unroll
      for (int ni = 0; ni < 4; ++ni) {
        short8_t vv = *(const short8_t*)&Vtl[(ni * 16 + l16) * TP2_ +
                                             half * 128 + ss * 32 + quad * 8];
        macc[ni] = __builtin_amdgcn_mfma_f32_16x16x32_bf16(ka, vv, macc[ni], 0, 0, 0);
      }
    }
    const int slot = stile * 2 + half;
    float* mdst = M + (((size_t)((slot >> 4) * H_ + h)) * 4096);
#pragma unroll
    for (int ni = 0; ni < 4; ++ni) {
      int e = ni * 16 + l16;
#pragma unroll
      for (int r = 0; r < 4; ++r) {
        int f = fq * 16 + quad * 4 + r;
        unsafeAtomicAdd(&mdst[f * 64 + e], 0.125f * macc[ni][r]);
      }
    }
  }
}

// ---------------------------------------------------------------------------
// p_kernel: P[b][h*64+f][d] = sum_e M[b,h,f,e]*Wproj[h*64+e][d], written
// TRANSPOSED as Pt[b][d][h*64+f] bf16 (k-contiguous for out_mfma staging).
// grid = B*H*(D/64) = 512 blocks.
// ---------------------------------------------------------------------------
__global__ __launch_bounds__(256) void p_kernel(
    const float* __restrict__ M, const float* __restrict__ Wproj,
    unsigned short* __restrict__ Pt) {
  const int blk = blockIdx.x;
  const int dtile = blk & 15;
  const int h = (blk >> 4) & 15;
  const int b = blk >> 8;
  const int d0 = dtile * 64;
  const int tid = threadIdx.x;
  const int tx = tid & 15, ty = tid >> 4;
  __shared__ float Ms[64][68];  // A: [e][f] (transposed on store)
  __shared__ float Ws[64][68];  // B: [e][d]
  const size_t mbase = ((size_t)(b * H_ + h)) * HS_ * HS_;
#pragma unroll
  for (int i = 0; i < 16; ++i) {
    int idx = tid + i * 256;
    int f = idx >> 6, e = idx & 63;
    Ms[e][f] = M[mbase + idx];
    Ws[f][e] = Wproj[(size_t)(h * HS_ + f) * D_ + d0 + e];
  }
  __syncthreads();
  float acc[4][4] = {};
#pragma unroll
  for (int kk = 0; kk < 64; ++kk) {
    const float4 a4 = *(const float4*)&Ms[kk][ty * 4];
    const float4 b4 = *(const float4*)&Ws[kk][tx * 4];
    const float a[4] = {a4.x, a4.y, a4.z, a4.w};
    const float bb[4] = {b4.x, b4.y, b4.z, b4.w};
#pragma unroll
    for (int i = 0; i < 4; ++i)
#pragma unroll
      for (int j = 0; j < 4; ++j) acc[i][j] += a[i] * bb[j];
  }
  // transpose through LDS: trans[d][f] then linear bf16 rows
  __syncthreads();
#pragma unroll
  for (int i = 0; i < 4; ++i)
#pragma unroll
    for (int j = 0; j < 4; ++j)
      Ms[tx * 4 + j][ty * 4 + i] = acc[i][j];
  __syncthreads();
  {
    int c = tid >> 2, ch = tid & 3;  // row c (d-dim), 16-elem chunk of f-dim
    unsigned short* dst = Pt + ((size_t)(b * D_ + d0 + c)) * HD_ + h * 64 + ch * 16;
#pragma unroll
    for (int e = 0; e < 16; ++e) dst[e] = f32_to_bf16(Ms[c][ch * 16 + e]);
  }
}

// ---------------------------------------------------------------------------
// out_mfma (R10 = R9 deep 3-slot pipeline + XCD clustering):
// out[s][d] = bproj[d] + sum_j Vb[s][j]*Pt[b][d][j]. 128x128 tiles,
// grid 256 (1/CU), 512 threads, 8 waves as 2(M)x4(N), wave 64x32.
// 3 slots x 32 KB = 96 KB. vmcnt(4) once per K-tile; read-ahead frags.
// Block remap clusters 4 stiles x 8 ntiles per XCD: Vb strips L2-reused 8x,
// Pt panels 4x.
// ---------------------------------------------------------------------------
__global__ __launch_bounds__(512) void out_mfma_kernel(
    const unsigned short* __restrict__ Vb,   // [4096][1024]
    const unsigned short* __restrict__ Pt,   // [2][1024][1024]
    const float* __restrict__ bproj,
    float* __restrict__ out) {
  const int blk = blockIdx.x;
  const int xcd = blk & 7, o = blk >> 3;     // XCD-cluster remap (bijective)
  const int stile = xcd * 4 + (o & 3);       // 0..31
  const int ntile = o >> 2;                  // 0..7
  const int s0 = stile * 128;
  const int n0 = ntile * 128;
  const int b = s0 >> 11;
  const int tid = threadIdx.x;
  const int lane = tid & 63;
  const int wid = tid >> 6;                // 0..7
  const int wm = wid & 1, wn = wid >> 1;   // 2(M) x 4(N)
  const int quad = lane >> 4, l16 = lane & 15;
  const int xa = l16 & 7;

  __shared__ __align__(16) unsigned char smem[98304];   // 3 x (A 16K + B 16K)

  float4_t acc[4][2];
  const float4_t fz = {0.f, 0.f, 0.f, 0.f};
#pragma unroll
  for (int i = 0; i < 4; ++i)
#pragma unroll
    for (int j = 0; j < 2; ++j) acc[i][j] = fz;

  const unsigned short* Bpanel = Pt + (size_t)b * D_ * HD_;

  unsigned short* pc = (unsigned short*)(smem);
  unsigned short* pn = (unsigned short*)(smem + 32768);
  unsigned short* ps = (unsigned short*)(smem + 65536);

  // One stage unit = 64 rows x 64 k (8 KB). u<2: A (Vb rows); u>=2: B (Pt rows).
  auto stageu = [&](unsigned short* slot, int kt, int u) {
    const int k0 = kt * KS_;
    if (u < 2) {
      int rb = u * 64 + wid * 8;
      int r = rb + (lane >> 3);
      int ch = ((lane & 7) ^ (r & 7)) * 8;
      async_copy16(Vb + (size_t)(s0 + r) * HD_ + k0 + ch, slot + rb * KS_);
    } else {
      int rb = (u - 2) * 64 + wid * 8;
      int r = rb + (lane >> 3);
      int ch = ((lane & 7) ^ (r & 7)) * 8;
      async_copy16(Bpanel + (size_t)(n0 + r) * HD_ + k0 + ch,
                   slot + 8192 + rb * KS_);
    }
  };
  auto rdA = [&](const unsigned short* P, int mi, int ks) {
    return *(const short8_t*)(P + (wm * 64 + mi * 16 + l16) * KS_ +
                              ((ks * 4 + quad) ^ xa) * 8);
  };
  auto rdB = [&](const unsigned short* P, int ni, int ks) {
    return *(const short8_t*)(P + 8192 + (wn * 32 + ni * 16 + l16) * KS_ +
                              ((ks * 4 + quad) ^ xa) * 8);
  };

  short8_t a0[4], a1[4], b0[2], b1[2];

#pragma unroll
  for (int u = 0; u < 4; ++u) stageu(pc, 0, u);
#pragma unroll
  for (int u = 0; u < 4; ++u) stageu(pn, 1, u);
  WAITV4;
  BAR;
#pragma unroll
  for (int mi = 0; mi < 4; ++mi) a0[mi] = rdA(pc, mi, 0);
  b0[0] = rdB(pc, 0, 0); b0[1] = rdB(pc, 1, 0);

  for (int kt = 0; kt < 16; ++kt) {
    const bool st = (kt < 14);
    // ---- q0: MFMA ks0; read ks1 frags ----
    if (st) { stageu(ps, kt + 2, 0); stageu(ps, kt + 2, 1); }
    BAR; WAITL0; SCHEDB;
    PRIO1;
#pragma unroll
    for (int mi = 0; mi < 4; ++mi) {
      acc[mi][0] = __builtin_amdgcn_mfma_f32_16x16x32_bf16(a0[mi], b0[0], acc[mi][0], 0, 0, 0);
      acc[mi][1] = __builtin_amdgcn_mfma_f32_16x16x32_bf16(a0[mi], b0[1], acc[mi][1], 0, 0, 0);
    }
    PRIO0;
#pragma unroll
    for (int mi = 0; mi < 4; ++mi) a1[mi] = rdA(pc, mi, 1);
    b1[0] = rdB(pc, 0, 1); b1[1] = rdB(pc, 1, 1);
    // ---- q1: drain kt+1; MFMA ks1; boundary read (kt+1, ks0) ----
    if (st) { stageu(ps, kt + 2, 2); stageu(ps, kt + 2, 3); }
    if (kt < 14) { WAITV4; } else if (kt == 14) { WAITV0; }
    BAR; WAITL0; SCHEDB;
    PRIO1;
#pragma unroll
    for (int mi = 0; mi < 4; ++mi) {
      acc[mi][0] = __builtin_amdgcn_mfma_f32_16x16x32_bf16(a1[mi], b1[0], acc[mi][0], 0, 0, 0);
      acc[mi][1] = __builtin_amdgcn_mfma_f32_16x16x32_bf16(a1[mi], b1[1], acc[mi][1], 0, 0, 0);
    }
    PRIO0;
    if (kt < 15) {
#pragma unroll
      for (int mi = 0; mi < 4; ++mi) a0[mi] = rdA(pn, mi, 0);
      b0[0] = rdB(pn, 0, 0); b0[1] = rdB(pn, 1, 0);
    }
    unsigned short* t = pc; pc = pn; pn = ps; ps = t;
  }

#pragma unroll
  for (int ni = 0; ni < 2; ++ni) {
    int col = n0 + wn * 32 + ni * 16 + l16;
    float bias = bproj[col];
#pragma unroll
    for (int mi = 0; mi < 4; ++mi) {
      int rowb = s0 + wm * 64 + mi * 16 + quad * 4;
#pragma unroll
      for (int r = 0; r < 4; ++r)
        out[(size_t)(rowb + r) * D_ + col] = acc[mi][ni][r] + bias;
    }
  }
}

extern "C" void kernel_launch(void* const* d_in, const int* in_sizes, int n_in,
                              void* d_out, int out_size, void* d_ws, size_t ws_size,
                              hipStream_t stream) {
  const float* x = (const float*)d_in[0];
  const float* Wk = (const float*)d_in[1];
  const float* Wv = (const float*)d_in[2];
  const float* Wproj = (const float*)d_in[3];
  const float* bproj = (const float*)d_in[4];
  float* out = (float*)d_out;

  // Workspace layout (~24.5 MB); every element written before read
  // (M is zeroed by prep, accumulated by kv, read by p).
  char* ws = (char*)d_ws;
  unsigned short* xb = (unsigned short*)ws;                  // 4M bf16 = 8 MB
  unsigned short* Wkvt = xb + (size_t)BS_ * D_;              // 2M bf16 = 4 MB
  unsigned short* Vb = Wkvt + (size_t)H_ * 128 * D_;         // 4M bf16 = 8 MB
  float* M = (float*)(Vb + (size_t)BS_ * HD_);               // 128K f32 = 0.5 MB
  unsigned short* Pt = (unsigned short*)(M + (size_t)B_ * H_ * 4096);  // 2M bf16 = 4 MB

  prep_kernel<<<dim3(4096 + H_ * (D_ / 64) + 128), dim3(256), 0, stream>>>(
      x, Wk, Wv, xb, Wkvt, M);
  kv_mfma_kernel<<<dim3(256), dim3(512), 0, stream>>>(xb, Wkvt, Vb, M);
  p_kernel<<<dim3(B_ * H_ * (D_ / 64)), dim3(256), 0, stream>>>(M, Wproj, Pt);
  out_mfma_kernel<<<dim3(256), dim3(512), 0, stream>>>(Vb, Pt, bproj, out);
}